// Round 11
// baseline (339.901 us; speedup 1.0000x reference)
//
#include <hip/hip_runtime.h>
#include <hip/hip_bf16.h>

// ---------- types ----------
using short8  = __attribute__((ext_vector_type(8))) short;
using ushort8 = __attribute__((ext_vector_type(8))) unsigned short;
using us4     = __attribute__((ext_vector_type(4))) unsigned short;
using f32x4   = __attribute__((ext_vector_type(4))) float;

#define GLB(p)  ((const __attribute__((address_space(1))) void*)(p))
#define LDSP(p) ((__attribute__((address_space(3))) void*)(p))

static __device__ __forceinline__ unsigned short f2bf(float f) {
    union { float f; unsigned u; } v; v.f = f;
    unsigned u = v.u;
    u += 0x7fffu + ((u >> 16) & 1u);   // round-to-nearest-even
    return (unsigned short)(u >> 16);
}
static __device__ __forceinline__ unsigned short f2bfc(float f) {
    return __builtin_bit_cast(unsigned short, __float2bfloat16(f));  // RNE; compiler emits cvt_pk
}

// ---------- problem constants ----------
#define K_DIM 2048
#define N_DIM 2048
#define M_TOTAL 26112
#define N_GROUPS 8

// ---------- kernel 1: B [K][N] fp32 -> Bt [N][K] bf16 (transpose + convert) ----------
__global__ __launch_bounds__(256) void cvt_bt_kernel(const float* __restrict__ B,
                                                     unsigned short* __restrict__ Bt) {
    __shared__ float t[32][33];
    int bx = blockIdx.x, by = blockIdx.y;
    int tx = threadIdx.x, ty = threadIdx.y;
#pragma unroll
    for (int i = 0; i < 32; i += 8)
        t[ty + i][tx] = B[(long)(by * 32 + ty + i) * N_DIM + bx * 32 + tx];
    __syncthreads();
#pragma unroll
    for (int i = 0; i < 32; i += 8)
        Bt[(long)(bx * 32 + ty + i) * K_DIM + by * 32 + tx] = f2bf(t[tx][ty + i]);
}

// ---------- kernel 2: fused GEMM (A fp32->bf16 in-kernel) + quarter-tile tail ----------
// C[M][N] fp32 = A(fp32 groups)[M][K] * Bt[N][K]^T bf16.  256x256 tile, BK=64,
// 8 waves, 128 KiB LDS dbuf, raw s_barrier, counted vmcnt, XOR-swizzled LDS.
// B: global_load_lds (pre-swizzled source, linear dest).  A: 8 plain float4 loads
// issued at ph1 for tile T+2 (pinned with sched_barrier; ~3.5-phase lead), then
// VMC(4)+sched_barrier+cvt+swizzled ds_write_b64 at ph4 into the buffer whose
// A-reads completed at ph3 (cross-wave visibility: writer's lgkm drains before its
// next phase's MFMA wait, >=5 barriers before the reader).
// Write side satisfies the reader's involution LDS[r][c^(r&7)] = A[r][c]
// (row&7 == ar0&7 for all written rows since row offsets are multiples of 32).
// vmcnt ledger (full tiles): entering tile T: B(T+1)=4 outstanding; ph1 +8 A;
// ph3 +2 B; ph4 +2 B -> VMC(4) drains B(T+1)+A(T+2), keeps B(T+2)=4.  Prologue:
// A(0)x8, A(1)x8, B(0)x4, B(1)x4 -> VMC(8) = A done; write A0,A1; VMC(4) = B0
// done; lgkmcnt(0); barrier.  Quarter tiles: same with 2 A-loads (VMC ledger
// 12 -> VMC(8) -> VMC(4)).

#define PBAR()  __builtin_amdgcn_s_barrier()
#define LGKM0() asm volatile("s_waitcnt lgkmcnt(0)" ::: "memory")
#define VMC(n)  asm volatile("s_waitcnt vmcnt(" #n ")" ::: "memory")
#define SBAR0() __builtin_amdgcn_sched_barrier(0)

#define ST_B(BUF, H, L, TT)                                                        \
    __builtin_amdgcn_global_load_lds(                                              \
        GLB(bSt + (long)((H) * 128 + (L) * 64) * K_DIM + (TT) * 64),               \
        LDSP(lds + (BUF) * 32768 + 16384 + (H) * 8192 + (L) * 4096 + w * 512), 16, 0, 0)

#define MMQ(MH, NH, AV, BV)                                                        \
    _Pragma("unroll") for (int i = 0; i < 4; ++i)                                  \
    _Pragma("unroll") for (int j = 0; j < 2; ++j)                                  \
        acc[(MH) * 4 + i][(NH) * 2 + j] = __builtin_amdgcn_mfma_f32_16x16x32_bf16( \
            AV[i], BV[j], acc[(MH) * 4 + i][(NH) * 2 + j], 0, 0, 0);

// issue N_I float4 A-loads for k-tile T2 (rows ar0+32i, 4 rows x 256B per instr)
#define ALD(AR, N_I, T2)                                                           \
    do { _Pragma("unroll") for (int i = 0; i < (N_I); ++i)                         \
            AR[i] = *(const float4*)(aB + (long)(i * 32) * K_DIM + (T2) * 64);     \
        SBAR0(); } while (0)

// convert + swizzled ds_write_b64 into BASE's A region (rows ar0+32i)
#define AWRN(BASE, AR, N_I)                                                        \
    do { _Pragma("unroll") for (int i = 0; i < (N_I); ++i) {                       \
        us4 o = { f2bfc(AR[i].x), f2bfc(AR[i].y), f2bfc(AR[i].z), f2bfc(AR[i].w) };\
        *(us4*)(lds + (BASE) + (ar0 + i * 32) * 64 + awch * 8 + wsub) = o;         \
    } } while (0)

// full 256x256 K-tile, 4 phases
#define TILE(BUF, T, DOA, DOB)                                                          \
    do {                                                                                \
        const unsigned short* pA = lds + (BUF) * 32768 + wm * 1024 + r16 * 64;          \
        const unsigned short* pB = lds + (BUF) * 32768 + 16384 + wn * 1024 + r16 * 64;  \
        short8 a0[4], a1[4], b00[2], b01[2], b10[2], b11[2];                            \
        float4 ar[8];                                                                   \
        /* ph1: read A-h0 + B-h0; issue A(T+2) fp32 loads; MFMA m0n0 */                 \
        _Pragma("unroll") for (int i = 0; i < 4; ++i) {                                 \
            a0[i] = *(const short8*)(pA + i * 2048 + c0 * 8);                           \
            a1[i] = *(const short8*)(pA + i * 2048 + c1 * 8);                           \
        }                                                                               \
        _Pragma("unroll") for (int j = 0; j < 2; ++j) {                                 \
            b00[j] = *(const short8*)(pB + j * 4096 + c0 * 8);                          \
            b01[j] = *(const short8*)(pB + j * 4096 + c1 * 8);                          \
        }                                                                               \
        if (DOA) ALD(ar, 8, (T) + 2);                                                   \
        PBAR();                                                                         \
        __builtin_amdgcn_s_setprio(1); MMQ(0, 0, a0, b00); MMQ(0, 0, a1, b01);          \
        __builtin_amdgcn_s_setprio(0); PBAR();                                          \
        /* ph2: read B-h1; MFMA m0n1 */                                                 \
        _Pragma("unroll") for (int j = 0; j < 2; ++j) {                                 \
            b10[j] = *(const short8*)(pB + 8192 + j * 4096 + c0 * 8);                   \
            b11[j] = *(const short8*)(pB + 8192 + j * 4096 + c1 * 8);                   \
        }                                                                               \
        PBAR();                                                                         \
        __builtin_amdgcn_s_setprio(1); MMQ(0, 1, a0, b10); MMQ(0, 1, a1, b11);          \
        __builtin_amdgcn_s_setprio(0); PBAR();                                          \
        /* ph3: read A-h1; stage B(T+2)-h0; MFMA m1n0 */                                \
        _Pragma("unroll") for (int i = 0; i < 4; ++i) {                                 \
            a0[i] = *(const short8*)(pA + 8192 + i * 2048 + c0 * 8);                    \
            a1[i] = *(const short8*)(pA + 8192 + i * 2048 + c1 * 8);                    \
        }                                                                               \
        if (DOB) { ST_B((BUF), 0, 0, (T) + 2); ST_B((BUF), 0, 1, (T) + 2); }            \
        PBAR();                                                                         \
        __builtin_amdgcn_s_setprio(1); MMQ(1, 0, a0, b00); MMQ(1, 0, a1, b01);          \
        __builtin_amdgcn_s_setprio(0); PBAR();                                          \
        /* ph4: stage B(T+2)-h1; MFMA m1n1; drain A regs, cvt, swizzled ds_write */     \
        if (DOB) { ST_B((BUF), 1, 0, (T) + 2); ST_B((BUF), 1, 1, (T) + 2); }            \
        __builtin_amdgcn_s_setprio(1); MMQ(1, 1, a0, b10); MMQ(1, 1, a1, b11);          \
        __builtin_amdgcn_s_setprio(0);                                                  \
        if (DOA) { VMC(4); SBAR0(); AWRN((BUF) * 32768, ar, 8); }                       \
    } while (0)

// ---- 64-row quarter tile: A 2x4096 shorts @0, B 2x16384 shorts @8192 ----
#define ST_B4(BUF, H, L, TT)                                                       \
    __builtin_amdgcn_global_load_lds(                                              \
        GLB(bSt + (long)((H) * 128 + (L) * 64) * K_DIM + (TT) * 64),               \
        LDSP(lds + 8192 + (BUF) * 16384 + (H) * 8192 + (L) * 4096 + w * 512), 16, 0, 0)

#define MMQ4(NH, AV, BV)                                                           \
    _Pragma("unroll") for (int i = 0; i < 2; ++i)                                  \
    _Pragma("unroll") for (int j = 0; j < 2; ++j)                                  \
        acc[i][(NH) * 2 + j] = __builtin_amdgcn_mfma_f32_16x16x32_bf16(            \
            AV[i], BV[j], acc[i][(NH) * 2 + j], 0, 0, 0);

#define TILE64(BUF, T, DOA, DOB)                                                        \
    do {                                                                                \
        const unsigned short* pA = lds + (BUF) * 4096 + wm * 1024 + r16 * 64;           \
        const unsigned short* pB = lds + 8192 + (BUF) * 16384 + wn * 1024 + r16 * 64;   \
        short8 a0[2], a1[2], b00[2], b01[2], b10[2], b11[2];                            \
        float4 ar[2];                                                                   \
        /* ph1: read A (both frags/ksteps) + B-h0; issue A(T+2); MFMA */                \
        _Pragma("unroll") for (int i = 0; i < 2; ++i) {                                 \
            a0[i] = *(const short8*)(pA + i * 2048 + c0 * 8);                           \
            a1[i] = *(const short8*)(pA + i * 2048 + c1 * 8);                           \
        }                                                                               \
        _Pragma("unroll") for (int j = 0; j < 2; ++j) {                                 \
            b00[j] = *(const short8*)(pB + j * 4096 + c0 * 8);                          \
            b01[j] = *(const short8*)(pB + j * 4096 + c1 * 8);                          \
        }                                                                               \
        if (DOA) ALD(ar, 2, (T) + 2);                                                   \
        PBAR();                                                                         \
        __builtin_amdgcn_s_setprio(1); MMQ4(0, a0, b00);                                \
        __builtin_amdgcn_s_setprio(0); PBAR();                                          \
        /* ph2: read B-h1; MFMA */                                                      \
        _Pragma("unroll") for (int j = 0; j < 2; ++j) {                                 \
            b10[j] = *(const short8*)(pB + 8192 + j * 4096 + c0 * 8);                   \
            b11[j] = *(const short8*)(pB + 8192 + j * 4096 + c1 * 8);                   \
        }                                                                               \
        PBAR();                                                                         \
        __builtin_amdgcn_s_setprio(1); MMQ4(0, a1, b01);                                \
        __builtin_amdgcn_s_setprio(0); PBAR();                                          \
        /* ph3: stage B(T+2)-h0; MFMA */                                                \
        if (DOB) { ST_B4((BUF), 0, 0, (T) + 2); ST_B4((BUF), 0, 1, (T) + 2); }          \
        PBAR();                                                                         \
        __builtin_amdgcn_s_setprio(1); MMQ4(1, a0, b10);                                \
        __builtin_amdgcn_s_setprio(0); PBAR();                                          \
        /* ph4: stage B(T+2)-h1; MFMA; drain + cvt + write A(T+2) */                    \
        if (DOB) { ST_B4((BUF), 1, 0, (T) + 2); ST_B4((BUF), 1, 1, (T) + 2); }          \
        __builtin_amdgcn_s_setprio(1); MMQ4(1, a1, b11);                                \
        __builtin_amdgcn_s_setprio(0);                                                  \
        if (DOA) { VMC(4); SBAR0(); AWRN((BUF) * 4096, ar, 2); }                        \
    } while (0)

__global__ __launch_bounds__(512, 2) void gemm8_kernel(
        const float* __restrict__ A0, const float* __restrict__ A1,
        const float* __restrict__ A2, const float* __restrict__ A3,
        const float* __restrict__ A4, const float* __restrict__ A5,
        const float* __restrict__ A6, const float* __restrict__ A7,
        const unsigned short* __restrict__ Bt, float* __restrict__ C) {
    __shared__ unsigned short lds[65536];   // 128 KiB

    int wg  = blockIdx.x;
    int tid = threadIdx.x;
    int l   = tid & 63;
    int w   = tid >> 6;          // wave 0..7
    int wm  = w >> 2;            // 0..1
    int wn  = w & 3;             // 0..3
    int r16 = l & 15, kq = l >> 4, x = l & 7;
    int c0  = kq ^ x;            // swizzled chunk, k-step 0
    int c1  = (4 + kq) ^ x;      // swizzled chunk, k-step 1
    int srow = tid >> 3;
    int sq   = (tid & 7) ^ (srow & 7);

    // A-convert geometry: instr i covers rows ar0+32i (4 rows x 256B contiguous)
    int c4   = l & 15;                 // float4 column (k = c4*4 .. +3)
    int ar0  = w * 4 + (l >> 4);       // row base 0..31
    int awch = (c4 >> 1) ^ (ar0 & 7);  // swizzled 16B chunk; (ar0+32i)&7 == ar0&7
    int wsub = (c4 & 1) * 4;           // short offset within chunk

    if (wg < 768) {
        // ---------- full 256x256 tile ----------
        int swz = (wg & 7) * 102 + (wg >> 3);
        int mt  = swz >> 3, nt = swz & 7;
        int m0  = mt * 256, n0 = nt * 256;

        const float* aBase; int goff;
        if      (mt < 16) { aBase = A0; goff = 0;     }
        else if (mt < 24) { aBase = A1; goff = 4096;  }
        else if (mt < 28) { aBase = A2; goff = 6144;  }
        else if (mt < 60) { aBase = A3; goff = 7168;  }
        else if (mt < 62) { aBase = A4; goff = 15360; }
        else if (mt < 74) { aBase = A5; goff = 15872; }
        else if (mt < 98) { aBase = A6; goff = 18944; }
        else              { aBase = A7; goff = 25088; }
        const float* aB = aBase + (long)(m0 - goff + ar0) * K_DIM + c4 * 4;
        const unsigned short* bSt = Bt + (long)(n0 + srow) * K_DIM + sq * 8;

        f32x4 acc[8][4] = {};

        // prologue: A(0)x8, A(1)x8, B(0)x4, B(1)x4 -> 24 out; VMC(8) = A0+A1 done;
        // write A0->buf0, A1->buf1; VMC(4) = B0 done (B1 in flight); lgkm0; barrier.
        {
            float4 arA[8], arB[8];
#pragma unroll
            for (int i = 0; i < 8; ++i) arA[i] = *(const float4*)(aB + (long)(i * 32) * K_DIM);
#pragma unroll
            for (int i = 0; i < 8; ++i) arB[i] = *(const float4*)(aB + (long)(i * 32) * K_DIM + 64);
            SBAR0();
            ST_B(0, 0, 0, 0); ST_B(0, 0, 1, 0); ST_B(0, 1, 0, 0); ST_B(0, 1, 1, 0);
            ST_B(1, 0, 0, 1); ST_B(1, 0, 1, 1); ST_B(1, 1, 0, 1); ST_B(1, 1, 1, 1);
            VMC(8); SBAR0();
            AWRN(0, arA, 8);
            AWRN(32768, arB, 8);
            VMC(4); LGKM0(); PBAR();
        }

#pragma unroll 1
        for (int t = 0; t < 30; t += 2) {
            TILE(0, t, 1, 1);     PBAR();
            TILE(1, t + 1, 1, 1); PBAR();
        }
        TILE(0, 30, 0, 0); VMC(0); PBAR();
        TILE(1, 31, 0, 0);

        int orow = m0 + wm * 16 + (l >> 4) * 4;
        int ocol = n0 + wn * 16 + (l & 15);
#pragma unroll
        for (int i = 0; i < 8; ++i)
#pragma unroll
            for (int j = 0; j < 4; ++j)
#pragma unroll
                for (int q = 0; q < 4; ++q)
                    C[(long)(orow + i * 32 + q) * N_DIM + (ocol + j * 64)] = acc[i][j][q];
    } else {
        // ---------- 64x256 quarter-tile (tail M-split x4) ----------
        int k    = wg - 768;                 // 0..191
        int o    = 768 + (k >> 2);           // original tile id 768..815
        int qh   = k & 3;
        int swz  = (o & 7) * 102 + (o >> 3);
        int mt   = swz >> 3, nt = swz & 7;
        int m0   = mt * 256 + qh * 64, n0 = nt * 256;

        const float* aBase; int goff;
        if      (mt < 16) { aBase = A0; goff = 0;     }
        else if (mt < 24) { aBase = A1; goff = 4096;  }
        else if (mt < 28) { aBase = A2; goff = 6144;  }
        else if (mt < 60) { aBase = A3; goff = 7168;  }
        else if (mt < 62) { aBase = A4; goff = 15360; }
        else if (mt < 74) { aBase = A5; goff = 15872; }
        else if (mt < 98) { aBase = A6; goff = 18944; }
        else              { aBase = A7; goff = 25088; }
        const float* aB = aBase + (long)(m0 - goff + ar0) * K_DIM + c4 * 4;
        const unsigned short* bSt = Bt + (long)(n0 + srow) * K_DIM + sq * 8;

        f32x4 acc[2][4] = {};

        // prologue: A(0)x2, A(1)x2, B(0)x4, B(1)x4 -> 12 out; VMC(8) = A done;
        // write A0->buf0, A1->buf1; VMC(4) = B0 done; lgkm0; barrier.
        {
            float4 arA[2], arB[2];
#pragma unroll
            for (int i = 0; i < 2; ++i) arA[i] = *(const float4*)(aB + (long)(i * 32) * K_DIM);
#pragma unroll
            for (int i = 0; i < 2; ++i) arB[i] = *(const float4*)(aB + (long)(i * 32) * K_DIM + 64);
            SBAR0();
            ST_B4(0, 0, 0, 0); ST_B4(0, 0, 1, 0); ST_B4(0, 1, 0, 0); ST_B4(0, 1, 1, 0);
            ST_B4(1, 0, 0, 1); ST_B4(1, 0, 1, 1); ST_B4(1, 1, 0, 1); ST_B4(1, 1, 1, 1);
            VMC(8); SBAR0();
            AWRN(0, arA, 2);
            AWRN(4096, arB, 2);
            VMC(4); LGKM0(); PBAR();
        }

#pragma unroll 1
        for (int t = 0; t < 30; ++t) {
            TILE64(t & 1, t, 1, 1); PBAR();
        }
        TILE64(0, 30, 0, 0); VMC(0); PBAR();
        TILE64(1, 31, 0, 0);

        int orow = m0 + wm * 16 + (l >> 4) * 4;
        int ocol = n0 + wn * 16 + (l & 15);
#pragma unroll
        for (int i = 0; i < 2; ++i)
#pragma unroll
            for (int j = 0; j < 4; ++j)
#pragma unroll
                for (int q = 0; q < 4; ++q)
                    C[(long)(orow + i * 32 + q) * N_DIM + (ocol + j * 64)] = acc[i][j][q];
    }
}

// ---------- fallback: correct (slow) fp32 tiled GEMM, used only if ws too small ----------
__global__ void naive_gemm_kernel(const float* __restrict__ A, const float* __restrict__ B,
                                  float* __restrict__ C, int M) {
    __shared__ float As[16][16];
    __shared__ float Bs[16][17];
    int tx = threadIdx.x, ty = threadIdx.y;
    int row = blockIdx.y * 16 + ty;
    int col = blockIdx.x * 16 + tx;
    float s = 0.f;
    for (int k0 = 0; k0 < K_DIM; k0 += 16) {
        As[ty][tx] = A[(long)row * K_DIM + k0 + tx];
        Bs[ty][tx] = B[(long)(k0 + ty) * N_DIM + col];
        __syncthreads();
#pragma unroll
        for (int t = 0; t < 16; ++t) s += As[ty][t] * Bs[t][tx];
        __syncthreads();
    }
    C[(long)row * N_DIM + col] = s;
}

// ---------- host launcher ----------
extern "C" void kernel_launch(void* const* d_in, const int* in_sizes, int n_in,
                              void* d_out, int out_size, void* d_ws, size_t ws_size,
                              hipStream_t stream) {
    static const int g_m[N_GROUPS]   = {4096, 2048, 1024, 8192, 512, 3072, 6144, 1024};
    static const int g_off[N_GROUPS] = {0, 4096, 6144, 7168, 15360, 15872, 18944, 25088};

    float* C = (float*)d_out;
    const size_t need = (size_t)N_DIM * K_DIM * 2;   // Bt only

    if (ws_size >= need) {
        unsigned short* Bt = (unsigned short*)d_ws;
        cvt_bt_kernel<<<dim3(N_DIM / 32, K_DIM / 32), dim3(32, 8), 0, stream>>>(
            (const float*)d_in[8], Bt);
        gemm8_kernel<<<768 + 192, 512, 0, stream>>>(
            (const float*)d_in[0], (const float*)d_in[1], (const float*)d_in[2],
            (const float*)d_in[3], (const float*)d_in[4], (const float*)d_in[5],
            (const float*)d_in[6], (const float*)d_in[7], Bt, C);
    } else {
        for (int g = 0; g < N_GROUPS; ++g)
            naive_gemm_kernel<<<dim3(N_DIM / 16, g_m[g] / 16), dim3(16, 16), 0, stream>>>(
                (const float*)d_in[g], (const float*)d_in[8], C + (size_t)g_off[g] * N_DIM,
                g_m[g]);
    }
}

// Round 12
// 279.104 us; speedup vs baseline: 1.2178x; 1.2178x over previous
//
#include <hip/hip_runtime.h>
#include <hip/hip_bf16.h>

// ---------- types ----------
using short8  = __attribute__((ext_vector_type(8))) short;
using ushort8 = __attribute__((ext_vector_type(8))) unsigned short;
using f32x4   = __attribute__((ext_vector_type(4))) float;

#define GLB(p)  ((const __attribute__((address_space(1))) void*)(p))
#define LDSP(p) ((__attribute__((address_space(3))) void*)(p))

static __device__ __forceinline__ unsigned short f2bf(float f) {
    union { float f; unsigned u; } v; v.f = f;
    unsigned u = v.u;
    u += 0x7fffu + ((u >> 16) & 1u);   // round-to-nearest-even
    return (unsigned short)(u >> 16);
}

// ---------- problem constants ----------
#define K_DIM 2048
#define N_DIM 2048
#define M_TOTAL 26112
#define N_GROUPS 8

// ---------- kernel 1: merged convert, one launch ----------
// blocks 0..4095: B [K][N] fp32 -> Bt [N][K] bf16 (32x32 transpose tiles)
// blocks 4096..5727: A groups fp32 -> contiguous bf16 Acat (16 rows/block)
__global__ __launch_bounds__(256) void cvt_all(
        const float* __restrict__ A0, const float* __restrict__ A1,
        const float* __restrict__ A2, const float* __restrict__ A3,
        const float* __restrict__ A4, const float* __restrict__ A5,
        const float* __restrict__ A6, const float* __restrict__ A7,
        const float* __restrict__ B,
        unsigned short* __restrict__ Acat, unsigned short* __restrict__ Bt) {
    int b   = blockIdx.x;
    int tid = threadIdx.x;
    if (b < 4096) {
        // ---- B transpose tile: bx = n-stripe, by = k-stripe ----
        __shared__ float t[32][33];
        int bx = b & 63, by = b >> 6;
        int tx = tid & 31, ty = tid >> 5;   // 32 x 8
#pragma unroll
        for (int i = 0; i < 32; i += 8)
            t[ty + i][tx] = B[(long)(by * 32 + ty + i) * N_DIM + bx * 32 + tx];
        __syncthreads();
#pragma unroll
        for (int i = 0; i < 32; i += 8)
            Bt[(long)(bx * 32 + ty + i) * K_DIM + by * 32 + tx] = f2bf(t[tx][ty + i]);
    } else {
        // ---- A panel: 16 rows ----
        int ab = b - 4096;
        const float* src; int gb;   // group base (16-row units)
        if      (ab < 256)  { src = A0; gb = 0;    }
        else if (ab < 384)  { src = A1; gb = 256;  }
        else if (ab < 448)  { src = A2; gb = 384;  }
        else if (ab < 960)  { src = A3; gb = 448;  }
        else if (ab < 992)  { src = A4; gb = 960;  }
        else if (ab < 1184) { src = A5; gb = 992;  }
        else if (ab < 1568) { src = A6; gb = 1184; }
        else                { src = A7; gb = 1568; }
        const float* s    = src  + (long)(ab - gb) * 16 * K_DIM;
        unsigned short* d = Acat + (long)ab * 16 * K_DIM;
#pragma unroll 4
        for (int i = 0; i < 16; ++i) {
            long off = (long)i * K_DIM + tid * 8;
            float4 x = *(const float4*)(s + off);
            float4 y = *(const float4*)(s + off + 4);
            ushort8 o;
            o[0] = f2bf(x.x); o[1] = f2bf(x.y); o[2] = f2bf(x.z); o[3] = f2bf(x.w);
            o[4] = f2bf(y.x); o[5] = f2bf(y.y); o[6] = f2bf(y.z); o[7] = f2bf(y.w);
            *(ushort8*)(d + off) = o;
        }
    }
}

// ---------- kernel 2: 256x256 8-phase bf16 GEMM + 64-row quarter-tile tail ----------
// (round-10 proven structure, verbatim)
// C[M][N] fp32 = Acat[M][K] bf16 * Bt[N][K]^T bf16.  BK=64, 8 waves (2Mx4N),
// 128 KiB LDS double buffer, raw s_barrier, counted vmcnt, XOR-swizzled LDS.
// Blocks 0..767: full 256x256 tiles (= exactly 3 dispatch waves on 256 CUs).
// Blocks 768..959: 64x256 quarter-tiles of the 48 last-scheduled tiles.

#define PBAR() __builtin_amdgcn_s_barrier()
#define VMC(n)  asm volatile("s_waitcnt vmcnt(" #n ")" ::: "memory")

#define ST_A(BUF, H, L, TT)                                                        \
    __builtin_amdgcn_global_load_lds(                                              \
        GLB(aSt + (long)((H) * 128 + (L) * 64) * K_DIM + (TT) * 64),               \
        LDSP(lds + (BUF) * 32768 + (H) * 8192 + (L) * 4096 + w * 512), 16, 0, 0)
#define ST_B(BUF, H, L, TT)                                                        \
    __builtin_amdgcn_global_load_lds(                                              \
        GLB(bSt + (long)((H) * 128 + (L) * 64) * K_DIM + (TT) * 64),               \
        LDSP(lds + (BUF) * 32768 + 16384 + (H) * 8192 + (L) * 4096 + w * 512), 16, 0, 0)

#define MMQ(MH, NH, AV, BV)                                                        \
    _Pragma("unroll") for (int i = 0; i < 4; ++i)                                  \
    _Pragma("unroll") for (int j = 0; j < 2; ++j)                                  \
        acc[(MH) * 4 + i][(NH) * 2 + j] = __builtin_amdgcn_mfma_f32_16x16x32_bf16( \
            AV[i], BV[j], acc[(MH) * 4 + i][(NH) * 2 + j], 0, 0, 0);

#define TILE(BUF, T, DO1, DO2)                                                          \
    do {                                                                                \
        const unsigned short* pA = lds + (BUF) * 32768 + wm * 1024 + r16 * 64;          \
        const unsigned short* pB = lds + (BUF) * 32768 + 16384 + wn * 1024 + r16 * 64;  \
        short8 a0[4], a1[4], b00[2], b01[2], b10[2], b11[2];                            \
        /* ph1: read A-h0 + B-h0; stage A(T+1)-h1 -> buf^1; MFMA m0n0 */                \
        _Pragma("unroll") for (int i = 0; i < 4; ++i) {                                 \
            a0[i] = *(const short8*)(pA + i * 2048 + c0 * 8);                           \
            a1[i] = *(const short8*)(pA + i * 2048 + c1 * 8);                           \
        }                                                                               \
        _Pragma("unroll") for (int j = 0; j < 2; ++j) {                                 \
            b00[j] = *(const short8*)(pB + j * 4096 + c0 * 8);                          \
            b01[j] = *(const short8*)(pB + j * 4096 + c1 * 8);                          \
        }                                                                               \
        if (DO1) { ST_A((BUF) ^ 1, 1, 0, (T) + 1); ST_A((BUF) ^ 1, 1, 1, (T) + 1); }    \
        PBAR();                                                                         \
        __builtin_amdgcn_s_setprio(1); MMQ(0, 0, a0, b00); MMQ(0, 0, a1, b01);          \
        __builtin_amdgcn_s_setprio(0); PBAR();                                          \
        /* ph2: read B-h1; stage A(T+2)-h0 -> buf; MFMA m0n1 */                         \
        _Pragma("unroll") for (int j = 0; j < 2; ++j) {                                 \
            b10[j] = *(const short8*)(pB + 8192 + j * 4096 + c0 * 8);                   \
            b11[j] = *(const short8*)(pB + 8192 + j * 4096 + c1 * 8);                   \
        }                                                                               \
        if (DO2) { ST_A((BUF), 0, 0, (T) + 2); ST_A((BUF), 0, 1, (T) + 2); }            \
        PBAR();                                                                         \
        __builtin_amdgcn_s_setprio(1); MMQ(0, 1, a0, b10); MMQ(0, 1, a1, b11);          \
        __builtin_amdgcn_s_setprio(0); PBAR();                                          \
        /* ph3: read A-h1; stage B(T+2)-h0 -> buf; MFMA m1n0 */                         \
        _Pragma("unroll") for (int i = 0; i < 4; ++i) {                                 \
            a0[i] = *(const short8*)(pA + 8192 + i * 2048 + c0 * 8);                    \
            a1[i] = *(const short8*)(pA + 8192 + i * 2048 + c1 * 8);                    \
        }                                                                               \
        if (DO2) { ST_B((BUF), 0, 0, (T) + 2); ST_B((BUF), 0, 1, (T) + 2); }            \
        PBAR();                                                                         \
        __builtin_amdgcn_s_setprio(1); MMQ(1, 0, a0, b00); MMQ(1, 0, a1, b01);          \
        __builtin_amdgcn_s_setprio(0); PBAR();                                          \
        /* ph4: register-only; stage B(T+2)-h1 -> buf; MFMA m1n1 */                     \
        if (DO2) { ST_B((BUF), 1, 0, (T) + 2); ST_B((BUF), 1, 1, (T) + 2); }            \
        __builtin_amdgcn_s_setprio(1); MMQ(1, 1, a0, b10); MMQ(1, 1, a1, b11);          \
        __builtin_amdgcn_s_setprio(0);                                                  \
    } while (0)

// ---- 64-row quarter tile: LDS = A 2x4096 shorts @0, B 2x16384 shorts @8192 ----
#define ST_A4(BUF, TT)                                                             \
    __builtin_amdgcn_global_load_lds(                                              \
        GLB(aSt + (long)(TT) * 64),                                                \
        LDSP(lds + (BUF) * 4096 + w * 512), 16, 0, 0)
#define ST_B4(BUF, H, L, TT)                                                       \
    __builtin_amdgcn_global_load_lds(                                              \
        GLB(bSt + (long)((H) * 128 + (L) * 64) * K_DIM + (TT) * 64),               \
        LDSP(lds + 8192 + (BUF) * 16384 + (H) * 8192 + (L) * 4096 + w * 512), 16, 0, 0)

#define MMQ4(NH, AV, BV)                                                           \
    _Pragma("unroll") for (int i = 0; i < 2; ++i)                                  \
    _Pragma("unroll") for (int j = 0; j < 2; ++j)                                  \
        acc[i][(NH) * 2 + j] = __builtin_amdgcn_mfma_f32_16x16x32_bf16(            \
            AV[i], BV[j], acc[i][(NH) * 2 + j], 0, 0, 0);

#define TILE64(BUF, T, DO2)                                                             \
    do {                                                                                \
        const unsigned short* pA = lds + (BUF) * 4096 + wm * 1024 + r16 * 64;           \
        const unsigned short* pB = lds + 8192 + (BUF) * 16384 + wn * 1024 + r16 * 64;   \
        short8 a0[2], a1[2], b00[2], b01[2], b10[2], b11[2];                            \
        /* ph1: read A (both m-frags, both k-steps) + B-h0; MFMA */                     \
        _Pragma("unroll") for (int i = 0; i < 2; ++i) {                                 \
            a0[i] = *(const short8*)(pA + i * 2048 + c0 * 8);                           \
            a1[i] = *(const short8*)(pA + i * 2048 + c1 * 8);                           \
        }                                                                               \
        _Pragma("unroll") for (int j = 0; j < 2; ++j) {                                 \
            b00[j] = *(const short8*)(pB + j * 4096 + c0 * 8);                          \
            b01[j] = *(const short8*)(pB + j * 4096 + c1 * 8);                          \
        }                                                                               \
        PBAR();                                                                         \
        __builtin_amdgcn_s_setprio(1); MMQ4(0, a0, b00);                                \
        __builtin_amdgcn_s_setprio(0); PBAR();                                          \
        /* ph2: read B-h1; MFMA */                                                      \
        _Pragma("unroll") for (int j = 0; j < 2; ++j) {                                 \
            b10[j] = *(const short8*)(pB + 8192 + j * 4096 + c0 * 8);                   \
            b11[j] = *(const short8*)(pB + 8192 + j * 4096 + c1 * 8);                   \
        }                                                                               \
        PBAR();                                                                         \
        __builtin_amdgcn_s_setprio(1); MMQ4(0, a1, b01);                                \
        __builtin_amdgcn_s_setprio(0); PBAR();                                          \
        /* ph3: stage B(T+2)-h0; MFMA */                                                \
        if (DO2) { ST_B4((BUF), 0, 0, (T) + 2); ST_B4((BUF), 0, 1, (T) + 2); }          \
        PBAR();                                                                         \
        __builtin_amdgcn_s_setprio(1); MMQ4(1, a0, b10);                                \
        __builtin_amdgcn_s_setprio(0); PBAR();                                          \
        /* ph4: stage B(T+2)-h1 + A(T+2); MFMA */                                       \
        if (DO2) { ST_B4((BUF), 1, 0, (T) + 2); ST_B4((BUF), 1, 1, (T) + 2);            \
                   ST_A4((BUF), (T) + 2); }                                             \
        __builtin_amdgcn_s_setprio(1); MMQ4(1, a1, b11);                                \
        __builtin_amdgcn_s_setprio(0);                                                  \
    } while (0)

__global__ __launch_bounds__(512, 2) void gemm8_kernel(const unsigned short* __restrict__ Acat,
                                                       const unsigned short* __restrict__ Bt,
                                                       float* __restrict__ C) {
    __shared__ unsigned short lds[65536];   // 128 KiB

    int wg  = blockIdx.x;
    int tid = threadIdx.x;
    int l   = tid & 63;
    int w   = tid >> 6;          // wave 0..7
    int wm  = w >> 2;            // 0..1
    int wn  = w & 3;             // 0..3
    int r16 = l & 15, kq = l >> 4, x = l & 7;
    int c0  = kq ^ x;            // swizzled chunk, k-step 0
    int c1  = (4 + kq) ^ x;      // swizzled chunk, k-step 1
    int srow = tid >> 3;
    int sq   = (tid & 7) ^ (srow & 7);

    if (wg < 768) {
        // ---------- full 256x256 tile ----------
        int swz = (wg & 7) * 102 + (wg >> 3);
        int mt  = swz >> 3, nt = swz & 7;
        int m0  = mt * 256, n0 = nt * 256;

        const unsigned short* aSt = Acat + (long)(m0 + srow) * K_DIM + sq * 8;
        const unsigned short* bSt = Bt   + (long)(n0 + srow) * K_DIM + sq * 8;

        f32x4 acc[8][4] = {};

        ST_A(0, 0, 0, 0); ST_A(0, 0, 1, 0); ST_A(0, 1, 0, 0); ST_A(0, 1, 1, 0);
        ST_B(0, 0, 0, 0); ST_B(0, 0, 1, 0); ST_B(0, 1, 0, 0); ST_B(0, 1, 1, 0);
        ST_A(1, 0, 0, 1); ST_A(1, 0, 1, 1);
        ST_B(1, 0, 0, 1); ST_B(1, 0, 1, 1); ST_B(1, 1, 0, 1); ST_B(1, 1, 1, 1);
        VMC(6); PBAR();

#pragma unroll 1
        for (int t = 0; t < 30; t += 2) {
            TILE(0, t, 1, 1);     VMC(6); PBAR();
            TILE(1, t + 1, 1, 1); VMC(6); PBAR();
        }
        TILE(0, 30, 1, 0); VMC(0); PBAR();
        TILE(1, 31, 0, 0);

        int orow = m0 + wm * 16 + (l >> 4) * 4;
        int ocol = n0 + wn * 16 + (l & 15);
#pragma unroll
        for (int i = 0; i < 8; ++i)
#pragma unroll
            for (int j = 0; j < 4; ++j)
#pragma unroll
                for (int q = 0; q < 4; ++q)
                    C[(long)(orow + i * 32 + q) * N_DIM + (ocol + j * 64)] = acc[i][j][q];
    } else {
        // ---------- 64x256 quarter-tile (tail M-split x4) ----------
        int k    = wg - 768;                 // 0..191
        int o    = 768 + (k >> 2);           // original tile id 768..815
        int qh   = k & 3;
        int swz  = (o & 7) * 102 + (o >> 3);
        int mt   = swz >> 3, nt = swz & 7;
        int m0   = mt * 256 + qh * 64, n0 = nt * 256;

        const unsigned short* aSt = Acat + (long)(m0 + srow) * K_DIM + sq * 8;
        const unsigned short* bSt = Bt   + (long)(n0 + srow) * K_DIM + sq * 8;

        f32x4 acc[2][4] = {};

        // prologue: T0 (5) + T1 (5); vmcnt(5) -> T0 complete
        ST_A4(0, 0);
        ST_B4(0, 0, 0, 0); ST_B4(0, 0, 1, 0); ST_B4(0, 1, 0, 0); ST_B4(0, 1, 1, 0);
        ST_A4(1, 1);
        ST_B4(1, 0, 0, 1); ST_B4(1, 0, 1, 1); ST_B4(1, 1, 0, 1); ST_B4(1, 1, 1, 1);
        VMC(5); PBAR();

#pragma unroll 1
        for (int t = 0; t < 30; ++t) {
            TILE64(t & 1, t, 1); VMC(5); PBAR();
        }
        TILE64(0, 30, 0); VMC(0); PBAR();
        TILE64(1, 31, 0);

        int orow = m0 + wm * 16 + (l >> 4) * 4;
        int ocol = n0 + wn * 16 + (l & 15);
#pragma unroll
        for (int i = 0; i < 2; ++i)
#pragma unroll
            for (int j = 0; j < 4; ++j)
#pragma unroll
                for (int q = 0; q < 4; ++q)
                    C[(long)(orow + i * 32 + q) * N_DIM + (ocol + j * 64)] = acc[i][j][q];
    }
}

// ---------- fallback: correct (slow) fp32 tiled GEMM, used only if ws too small ----------
__global__ void naive_gemm_kernel(const float* __restrict__ A, const float* __restrict__ B,
                                  float* __restrict__ C, int M) {
    __shared__ float As[16][16];
    __shared__ float Bs[16][17];
    int tx = threadIdx.x, ty = threadIdx.y;
    int row = blockIdx.y * 16 + ty;
    int col = blockIdx.x * 16 + tx;
    float s = 0.f;
    for (int k0 = 0; k0 < K_DIM; k0 += 16) {
        As[ty][tx] = A[(long)row * K_DIM + k0 + tx];
        Bs[ty][tx] = B[(long)(k0 + ty) * N_DIM + col];
        __syncthreads();
#pragma unroll
        for (int t = 0; t < 16; ++t) s += As[ty][t] * Bs[t][tx];
        __syncthreads();
    }
    C[(long)row * N_DIM + col] = s;
}

// ---------- host launcher ----------
extern "C" void kernel_launch(void* const* d_in, const int* in_sizes, int n_in,
                              void* d_out, int out_size, void* d_ws, size_t ws_size,
                              hipStream_t stream) {
    static const int g_m[N_GROUPS]   = {4096, 2048, 1024, 8192, 512, 3072, 6144, 1024};
    static const int g_off[N_GROUPS] = {0, 4096, 6144, 7168, 15360, 15872, 18944, 25088};

    float* C = (float*)d_out;
    const size_t need = ((size_t)M_TOTAL * K_DIM + (size_t)N_DIM * K_DIM) * 2;

    if (ws_size >= need) {
        unsigned short* Acat = (unsigned short*)d_ws;
        unsigned short* Bt   = Acat + (size_t)M_TOTAL * K_DIM;

        cvt_all<<<4096 + M_TOTAL / 16, 256, 0, stream>>>(
            (const float*)d_in[0], (const float*)d_in[1], (const float*)d_in[2],
            (const float*)d_in[3], (const float*)d_in[4], (const float*)d_in[5],
            (const float*)d_in[6], (const float*)d_in[7], (const float*)d_in[8],
            Acat, Bt);

        gemm8_kernel<<<768 + 192, 512, 0, stream>>>(Acat, Bt, C);
    } else {
        for (int g = 0; g < N_GROUPS; ++g)
            naive_gemm_kernel<<<dim3(N_DIM / 16, g_m[g] / 16), dim3(16, 16), 0, stream>>>(
                (const float*)d_in[g], (const float*)d_in[8], C + (size_t)g_off[g] * N_DIM,
                g_m[g]);
    }
}

// Round 13
// 275.327 us; speedup vs baseline: 1.2345x; 1.0137x over previous
//
#include <hip/hip_runtime.h>
#include <hip/hip_bf16.h>

// ---------- types ----------
using short8  = __attribute__((ext_vector_type(8))) short;
using ushort8 = __attribute__((ext_vector_type(8))) unsigned short;
using f32x4   = __attribute__((ext_vector_type(4))) float;

#define GLB(p)  ((const __attribute__((address_space(1))) void*)(p))
#define LDSP(p) ((__attribute__((address_space(3))) void*)(p))

static __device__ __forceinline__ unsigned short f2bf(float f) {
    union { float f; unsigned u; } v; v.f = f;
    unsigned u = v.u;
    u += 0x7fffu + ((u >> 16) & 1u);   // round-to-nearest-even
    return (unsigned short)(u >> 16);
}

// ---------- problem constants ----------
#define K_DIM 2048
#define N_DIM 2048
#define M_TOTAL 26112
#define N_GROUPS 8

// ---------- kernel 1: merged convert, one launch (r12 verbatim) ----------
// blocks 0..4095: B [K][N] fp32 -> Bt [N][K] bf16 (32x32 transpose tiles)
// blocks 4096..5727: A groups fp32 -> contiguous bf16 Acat (16 rows/block)
__global__ __launch_bounds__(256) void cvt_all(
        const float* __restrict__ A0, const float* __restrict__ A1,
        const float* __restrict__ A2, const float* __restrict__ A3,
        const float* __restrict__ A4, const float* __restrict__ A5,
        const float* __restrict__ A6, const float* __restrict__ A7,
        const float* __restrict__ B,
        unsigned short* __restrict__ Acat, unsigned short* __restrict__ Bt) {
    int b   = blockIdx.x;
    int tid = threadIdx.x;
    if (b < 4096) {
        __shared__ float t[32][33];
        int bx = b & 63, by = b >> 6;
        int tx = tid & 31, ty = tid >> 5;   // 32 x 8
#pragma unroll
        for (int i = 0; i < 32; i += 8)
            t[ty + i][tx] = B[(long)(by * 32 + ty + i) * N_DIM + bx * 32 + tx];
        __syncthreads();
#pragma unroll
        for (int i = 0; i < 32; i += 8)
            Bt[(long)(bx * 32 + ty + i) * K_DIM + by * 32 + tx] = f2bf(t[tx][ty + i]);
    } else {
        int ab = b - 4096;
        const float* src; int gb;   // group base (16-row units)
        if      (ab < 256)  { src = A0; gb = 0;    }
        else if (ab < 384)  { src = A1; gb = 256;  }
        else if (ab < 448)  { src = A2; gb = 384;  }
        else if (ab < 960)  { src = A3; gb = 448;  }
        else if (ab < 992)  { src = A4; gb = 960;  }
        else if (ab < 1184) { src = A5; gb = 992;  }
        else if (ab < 1568) { src = A6; gb = 1184; }
        else                { src = A7; gb = 1568; }
        const float* s    = src  + (long)(ab - gb) * 16 * K_DIM;
        unsigned short* d = Acat + (long)ab * 16 * K_DIM;
#pragma unroll 4
        for (int i = 0; i < 16; ++i) {
            long off = (long)i * K_DIM + tid * 8;
            float4 x = *(const float4*)(s + off);
            float4 y = *(const float4*)(s + off + 4);
            ushort8 o;
            o[0] = f2bf(x.x); o[1] = f2bf(x.y); o[2] = f2bf(x.z); o[3] = f2bf(x.w);
            o[4] = f2bf(y.x); o[5] = f2bf(y.y); o[6] = f2bf(y.z); o[7] = f2bf(y.w);
            *(ushort8*)(d + off) = o;
        }
    }
}

// ---------- kernel 2: 256x256 GEMM, barrier-thinned (4 barriers/tile) ----------
// vs r12: pre-MFMA barriers of ph1/ph2/ph3 removed (only post-MFMA barriers carry
// region safety: a stage into region R occurs >=1 all-waves barrier after R's
// consumption), and the tile-end VMC is hoisted into ph4 after its stages (drains
// the same 8-oldest = tile T+1's loads; overlap with ph4's 16 MFMAs).

#define PBAR() __builtin_amdgcn_s_barrier()
#define VMC(n)  asm volatile("s_waitcnt vmcnt(" #n ")" ::: "memory")

#define ST_A(BUF, H, L, TT)                                                        \
    __builtin_amdgcn_global_load_lds(                                              \
        GLB(aSt + (long)((H) * 128 + (L) * 64) * K_DIM + (TT) * 64),               \
        LDSP(lds + (BUF) * 32768 + (H) * 8192 + (L) * 4096 + w * 512), 16, 0, 0)
#define ST_B(BUF, H, L, TT)                                                        \
    __builtin_amdgcn_global_load_lds(                                              \
        GLB(bSt + (long)((H) * 128 + (L) * 64) * K_DIM + (TT) * 64),               \
        LDSP(lds + (BUF) * 32768 + 16384 + (H) * 8192 + (L) * 4096 + w * 512), 16, 0, 0)

#define MMQ(MH, NH, AV, BV)                                                        \
    _Pragma("unroll") for (int i = 0; i < 4; ++i)                                  \
    _Pragma("unroll") for (int j = 0; j < 2; ++j)                                  \
        acc[(MH) * 4 + i][(NH) * 2 + j] = __builtin_amdgcn_mfma_f32_16x16x32_bf16( \
            AV[i], BV[j], acc[(MH) * 4 + i][(NH) * 2 + j], 0, 0, 0);

// ledger (steady, DO1=DO2=1): entering tile = 6 outstanding (T+2 partial);
// ph1 +2 (A(T+1)h1), ph2 +2, ph3 +2, ph4 +2 -> 14; VMC(6) in ph4 drains the
// 8 oldest = ALL of tile T+1's loads, keeps 6 = tile T+2's.  DO2=0 -> no VMC
// inside (caller supplies VMC(0)).
#define TILE(BUF, T, DO1, DO2)                                                          \
    do {                                                                                \
        const unsigned short* pA = lds + (BUF) * 32768 + wm * 1024 + r16 * 64;          \
        const unsigned short* pB = lds + (BUF) * 32768 + 16384 + wn * 1024 + r16 * 64;  \
        short8 a0[4], a1[4], b00[2], b01[2], b10[2], b11[2];                            \
        /* ph1: read A-h0 + B-h0; stage A(T+1)-h1 -> buf^1; MFMA m0n0 (no pre-bar) */   \
        _Pragma("unroll") for (int i = 0; i < 4; ++i) {                                 \
            a0[i] = *(const short8*)(pA + i * 2048 + c0 * 8);                           \
            a1[i] = *(const short8*)(pA + i * 2048 + c1 * 8);                           \
        }                                                                               \
        _Pragma("unroll") for (int j = 0; j < 2; ++j) {                                 \
            b00[j] = *(const short8*)(pB + j * 4096 + c0 * 8);                          \
            b01[j] = *(const short8*)(pB + j * 4096 + c1 * 8);                          \
        }                                                                               \
        if (DO1) { ST_A((BUF) ^ 1, 1, 0, (T) + 1); ST_A((BUF) ^ 1, 1, 1, (T) + 1); }    \
        __builtin_amdgcn_s_setprio(1); MMQ(0, 0, a0, b00); MMQ(0, 0, a1, b01);          \
        __builtin_amdgcn_s_setprio(0); PBAR();                                          \
        /* ph2: read B-h1; stage A(T+2)-h0 -> buf (A-h0 consumed ph1, 1 bar ago) */     \
        _Pragma("unroll") for (int j = 0; j < 2; ++j) {                                 \
            b10[j] = *(const short8*)(pB + 8192 + j * 4096 + c0 * 8);                   \
            b11[j] = *(const short8*)(pB + 8192 + j * 4096 + c1 * 8);                   \
        }                                                                               \
        if (DO2) { ST_A((BUF), 0, 0, (T) + 2); ST_A((BUF), 0, 1, (T) + 2); }            \
        __builtin_amdgcn_s_setprio(1); MMQ(0, 1, a0, b10); MMQ(0, 1, a1, b11);          \
        __builtin_amdgcn_s_setprio(0); PBAR();                                          \
        /* ph3: read A-h1; stage B(T+2)-h0 -> buf (B-h0 consumed ph1) */                \
        _Pragma("unroll") for (int i = 0; i < 4; ++i) {                                 \
            a0[i] = *(const short8*)(pA + 8192 + i * 2048 + c0 * 8);                    \
            a1[i] = *(const short8*)(pA + 8192 + i * 2048 + c1 * 8);                    \
        }                                                                               \
        if (DO2) { ST_B((BUF), 0, 0, (T) + 2); ST_B((BUF), 0, 1, (T) + 2); }            \
        __builtin_amdgcn_s_setprio(1); MMQ(1, 0, a0, b00); MMQ(1, 0, a1, b01);          \
        __builtin_amdgcn_s_setprio(0); PBAR();                                          \
        /* ph4: stage B(T+2)-h1 (B-h1 consumed ph2); hoisted VMC(6); MFMA m1n1 */       \
        if (DO2) { ST_B((BUF), 1, 0, (T) + 2); ST_B((BUF), 1, 1, (T) + 2); VMC(6); }    \
        __builtin_amdgcn_s_setprio(1); MMQ(1, 1, a0, b10); MMQ(1, 1, a1, b11);          \
        __builtin_amdgcn_s_setprio(0);                                                  \
    } while (0)

// ---- 64-row quarter tile (tail), same thinning; 5 loads/tile, VMC(5) hoisted ----
#define ST_A4(BUF, TT)                                                             \
    __builtin_amdgcn_global_load_lds(                                              \
        GLB(aSt + (long)(TT) * 64),                                                \
        LDSP(lds + (BUF) * 4096 + w * 512), 16, 0, 0)
#define ST_B4(BUF, H, L, TT)                                                       \
    __builtin_amdgcn_global_load_lds(                                              \
        GLB(bSt + (long)((H) * 128 + (L) * 64) * K_DIM + (TT) * 64),               \
        LDSP(lds + 8192 + (BUF) * 16384 + (H) * 8192 + (L) * 4096 + w * 512), 16, 0, 0)

#define MMQ4(NH, AV, BV)                                                           \
    _Pragma("unroll") for (int i = 0; i < 2; ++i)                                  \
    _Pragma("unroll") for (int j = 0; j < 2; ++j)                                  \
        acc[i][(NH) * 2 + j] = __builtin_amdgcn_mfma_f32_16x16x32_bf16(            \
            AV[i], BV[j], acc[i][(NH) * 2 + j], 0, 0, 0);

#define TILE64(BUF, T, DO2)                                                             \
    do {                                                                                \
        const unsigned short* pA = lds + (BUF) * 4096 + wm * 1024 + r16 * 64;           \
        const unsigned short* pB = lds + 8192 + (BUF) * 16384 + wn * 1024 + r16 * 64;   \
        short8 a0[2], a1[2], b00[2], b01[2], b10[2], b11[2];                            \
        /* ph1: read A (all) + B-h0; MFMA (no pre-bar) */                               \
        _Pragma("unroll") for (int i = 0; i < 2; ++i) {                                 \
            a0[i] = *(const short8*)(pA + i * 2048 + c0 * 8);                           \
            a1[i] = *(const short8*)(pA + i * 2048 + c1 * 8);                           \
        }                                                                               \
        _Pragma("unroll") for (int j = 0; j < 2; ++j) {                                 \
            b00[j] = *(const short8*)(pB + j * 4096 + c0 * 8);                          \
            b01[j] = *(const short8*)(pB + j * 4096 + c1 * 8);                          \
        }                                                                               \
        __builtin_amdgcn_s_setprio(1); MMQ4(0, a0, b00);                                \
        __builtin_amdgcn_s_setprio(0); PBAR();                                          \
        /* ph2: read B-h1; MFMA */                                                      \
        _Pragma("unroll") for (int j = 0; j < 2; ++j) {                                 \
            b10[j] = *(const short8*)(pB + 8192 + j * 4096 + c0 * 8);                   \
            b11[j] = *(const short8*)(pB + 8192 + j * 4096 + c1 * 8);                   \
        }                                                                               \
        __builtin_amdgcn_s_setprio(1); MMQ4(0, a1, b01);                                \
        __builtin_amdgcn_s_setprio(0); PBAR();                                          \
        /* ph3: stage B(T+2)-h0 (consumed ph1); MFMA */                                 \
        if (DO2) { ST_B4((BUF), 0, 0, (T) + 2); ST_B4((BUF), 0, 1, (T) + 2); }          \
        __builtin_amdgcn_s_setprio(1); MMQ4(1, a0, b10);                                \
        __builtin_amdgcn_s_setprio(0); PBAR();                                          \
        /* ph4: stage B(T+2)-h1 + A(T+2) (consumed ph2/ph1); hoisted VMC(5); MFMA */    \
        if (DO2) { ST_B4((BUF), 1, 0, (T) + 2); ST_B4((BUF), 1, 1, (T) + 2);            \
                   ST_A4((BUF), (T) + 2); VMC(5); }                                     \
        __builtin_amdgcn_s_setprio(1); MMQ4(1, a1, b11);                                \
        __builtin_amdgcn_s_setprio(0);                                                  \
    } while (0)

__global__ __launch_bounds__(512, 2) void gemm8_kernel(const unsigned short* __restrict__ Acat,
                                                       const unsigned short* __restrict__ Bt,
                                                       float* __restrict__ C) {
    __shared__ unsigned short lds[65536];   // 128 KiB

    int wg  = blockIdx.x;
    int tid = threadIdx.x;
    int l   = tid & 63;
    int w   = tid >> 6;          // wave 0..7
    int wm  = w >> 2;            // 0..1
    int wn  = w & 3;             // 0..3
    int r16 = l & 15, kq = l >> 4, x = l & 7;
    int c0  = kq ^ x;            // swizzled chunk, k-step 0
    int c1  = (4 + kq) ^ x;      // swizzled chunk, k-step 1
    int srow = tid >> 3;
    int sq   = (tid & 7) ^ (srow & 7);

    if (wg < 768) {
        // ---------- full 256x256 tile ----------
        int swz = (wg & 7) * 102 + (wg >> 3);
        int mt  = swz >> 3, nt = swz & 7;
        int m0  = mt * 256, n0 = nt * 256;

        const unsigned short* aSt = Acat + (long)(m0 + srow) * K_DIM + sq * 8;
        const unsigned short* bSt = Bt   + (long)(n0 + srow) * K_DIM + sq * 8;

        f32x4 acc[8][4] = {};

        ST_A(0, 0, 0, 0); ST_A(0, 0, 1, 0); ST_A(0, 1, 0, 0); ST_A(0, 1, 1, 0);
        ST_B(0, 0, 0, 0); ST_B(0, 0, 1, 0); ST_B(0, 1, 0, 0); ST_B(0, 1, 1, 0);
        ST_A(1, 0, 0, 1); ST_A(1, 0, 1, 1);
        ST_B(1, 0, 0, 1); ST_B(1, 0, 1, 1); ST_B(1, 1, 0, 1); ST_B(1, 1, 1, 1);
        VMC(6); PBAR();

#pragma unroll 1
        for (int t = 0; t < 30; t += 2) {
            TILE(0, t, 1, 1);     PBAR();
            TILE(1, t + 1, 1, 1); PBAR();
        }
        TILE(0, 30, 1, 0); VMC(0); PBAR();
        TILE(1, 31, 0, 0);

        int orow = m0 + wm * 16 + (l >> 4) * 4;
        int ocol = n0 + wn * 16 + (l & 15);
#pragma unroll
        for (int i = 0; i < 8; ++i)
#pragma unroll
            for (int j = 0; j < 4; ++j)
#pragma unroll
                for (int q = 0; q < 4; ++q)
                    C[(long)(orow + i * 32 + q) * N_DIM + (ocol + j * 64)] = acc[i][j][q];
    } else {
        // ---------- 64x256 quarter-tile (tail M-split x4) ----------
        int k    = wg - 768;                 // 0..191
        int o    = 768 + (k >> 2);           // original tile id 768..815
        int qh   = k & 3;
        int swz  = (o & 7) * 102 + (o >> 3);
        int mt   = swz >> 3, nt = swz & 7;
        int m0   = mt * 256 + qh * 64, n0 = nt * 256;

        const unsigned short* aSt = Acat + (long)(m0 + srow) * K_DIM + sq * 8;
        const unsigned short* bSt = Bt   + (long)(n0 + srow) * K_DIM + sq * 8;

        f32x4 acc[2][4] = {};

        ST_A4(0, 0);
        ST_B4(0, 0, 0, 0); ST_B4(0, 0, 1, 0); ST_B4(0, 1, 0, 0); ST_B4(0, 1, 1, 0);
        ST_A4(1, 1);
        ST_B4(1, 0, 0, 1); ST_B4(1, 0, 1, 1); ST_B4(1, 1, 0, 1); ST_B4(1, 1, 1, 1);
        VMC(5); PBAR();

#pragma unroll 1
        for (int t = 0; t < 30; ++t) {
            TILE64(t & 1, t, 1); PBAR();
        }
        TILE64(0, 30, 0); VMC(0); PBAR();
        TILE64(1, 31, 0);

        int orow = m0 + wm * 16 + (l >> 4) * 4;
        int ocol = n0 + wn * 16 + (l & 15);
#pragma unroll
        for (int i = 0; i < 2; ++i)
#pragma unroll
            for (int j = 0; j < 4; ++j)
#pragma unroll
                for (int q = 0; q < 4; ++q)
                    C[(long)(orow + i * 32 + q) * N_DIM + (ocol + j * 64)] = acc[i][j][q];
    }
}

// ---------- fallback: correct (slow) fp32 tiled GEMM, used only if ws too small ----------
__global__ void naive_gemm_kernel(const float* __restrict__ A, const float* __restrict__ B,
                                  float* __restrict__ C, int M) {
    __shared__ float As[16][16];
    __shared__ float Bs[16][17];
    int tx = threadIdx.x, ty = threadIdx.y;
    int row = blockIdx.y * 16 + ty;
    int col = blockIdx.x * 16 + tx;
    float s = 0.f;
    for (int k0 = 0; k0 < K_DIM; k0 += 16) {
        As[ty][tx] = A[(long)row * K_DIM + k0 + tx];
        Bs[ty][tx] = B[(long)(k0 + ty) * N_DIM + col];
        __syncthreads();
#pragma unroll
        for (int t = 0; t < 16; ++t) s += As[ty][t] * Bs[t][tx];
        __syncthreads();
    }
    C[(long)row * N_DIM + col] = s;
}

// ---------- host launcher ----------
extern "C" void kernel_launch(void* const* d_in, const int* in_sizes, int n_in,
                              void* d_out, int out_size, void* d_ws, size_t ws_size,
                              hipStream_t stream) {
    static const int g_m[N_GROUPS]   = {4096, 2048, 1024, 8192, 512, 3072, 6144, 1024};
    static const int g_off[N_GROUPS] = {0, 4096, 6144, 7168, 15360, 15872, 18944, 25088};

    float* C = (float*)d_out;
    const size_t need = ((size_t)M_TOTAL * K_DIM + (size_t)N_DIM * K_DIM) * 2;

    if (ws_size >= need) {
        unsigned short* Acat = (unsigned short*)d_ws;
        unsigned short* Bt   = Acat + (size_t)M_TOTAL * K_DIM;

        cvt_all<<<4096 + M_TOTAL / 16, 256, 0, stream>>>(
            (const float*)d_in[0], (const float*)d_in[1], (const float*)d_in[2],
            (const float*)d_in[3], (const float*)d_in[4], (const float*)d_in[5],
            (const float*)d_in[6], (const float*)d_in[7], (const float*)d_in[8],
            Acat, Bt);

        gemm8_kernel<<<768 + 192, 512, 0, stream>>>(Acat, Bt, C);
    } else {
        for (int g = 0; g < N_GROUPS; ++g)
            naive_gemm_kernel<<<dim3(N_DIM / 16, g_m[g] / 16), dim3(16, 16), 0, stream>>>(
                (const float*)d_in[g], (const float*)d_in[8], C + (size_t)g_off[g] * N_DIM,
                g_m[g]);
    }
}